// Round 4
// baseline (2031.999 us; speedup 1.0000x reference)
//
#include <hip/hip_runtime.h>

// SignalingModel: X_{t+1} = mml(W @ X_t + X_bias), 60 steps, W 0.24% sparse.
// R1 (2nd resubmit after infra failures — container died pre-push both times):
// edge list in REGISTERS (40 edges/thread, zero-padded), scatter via LDS
// atomicAdd into a next-state buffer pre-initialized with X_bias. Fixed
// fully-unrolled inner loop — no global loads, no runtime trip counts.

#define NN 2048
#define STEPS 60
#define LEAKV 0.01f
#define EMAX 10240          // E; actual nnz <= EMAX (duplicate (tgt,src) collapse)
#define EPT 40              // EMAX / 256 edges per sim thread

__device__ __forceinline__ float mml_f(float x) {
  if (x < 0.0f)      return LEAKV * x;
  else if (x < 0.5f) return x;
  else               return 1.0f - 0.25f / x;
}

// --- build pipeline -------------------------------------------------------

// one wave per row: count nonzeros
__global__ __launch_bounds__(64) void count_row(const float* __restrict__ W,
                                                int* __restrict__ cnt) {
  const int n = blockIdx.x, lane = threadIdx.x;
  int c = 0;
  for (int c0 = 0; c0 < NN; c0 += 64) {
    float w = W[n * NN + c0 + lane];
    c += __popcll(__ballot(w != 0.0f));
  }
  if (lane == 0) cnt[n] = c;
}

// exclusive scan of 2048 counts, single block of 1024 threads
__global__ __launch_bounds__(1024) void scan2048(const int* __restrict__ cnt,
                                                 int* __restrict__ base) {
  __shared__ int sb[2][NN];
  const int t = threadIdx.x;
  sb[0][t] = cnt[t];
  sb[0][t + 1024] = cnt[t + 1024];
  __syncthreads();
  int p = 0;
  for (int off = 1; off < NN; off <<= 1) {
    int i0 = t, i1 = t + 1024;
    sb[p ^ 1][i0] = sb[p][i0] + (i0 >= off ? sb[p][i0 - off] : 0);
    sb[p ^ 1][i1] = sb[p][i1] + (i1 >= off ? sb[p][i1 - off] : 0);
    __syncthreads();
    p ^= 1;
  }
  base[t] = sb[p][t] - cnt[t];                    // inclusive -> exclusive
  base[t + 1024] = sb[p][t + 1024] - cnt[t + 1024];
}

// one wave per row: write (w, tgt<<16|src) at global ordinal (row-major order)
__global__ __launch_bounds__(64) void fill_edges(const float* __restrict__ W,
                                                 const int* __restrict__ base,
                                                 float* __restrict__ ew,
                                                 unsigned int* __restrict__ epack) {
  const int n = blockIdx.x, lane = threadIdx.x;
  const int b = base[n];
  int off = 0;
  for (int c0 = 0; c0 < NN; c0 += 64) {
    float w = W[n * NN + c0 + lane];
    unsigned long long m = __ballot(w != 0.0f);
    if (w != 0.0f) {
      int e = b + off + __popcll(m & ((1ull << lane) - 1ull));
      ew[e] = w;
      epack[e] = ((unsigned)n << 16) | (unsigned)(c0 + lane);
    }
    off += __popcll(m);
  }
}

// --- simulation -----------------------------------------------------------
// one block per sample; state ping-pong in LDS; 40 reg-resident edges/thread.
__global__ __launch_bounds__(256) void sim(const float* __restrict__ Xfull,
                                           const float* __restrict__ bias,
                                           const float* __restrict__ ew,
                                           const unsigned int* __restrict__ epack,
                                           float* __restrict__ out) {
  __shared__ float X2[2][NN];
  const int t = (int)threadIdx.x;
  const int s = (int)blockIdx.x;

  // hoist edge structure into registers (coalesced: e = k*256 + t)
  float w[EPT];
  unsigned int p[EPT];
#pragma unroll
  for (int k = 0; k < EPT; ++k) {
    w[k] = ew[k * 256 + t];
    p[k] = epack[k * 256 + t];
  }

  float xb[8];
#pragma unroll
  for (int j = 0; j < 8; ++j) {
    const int n = j * 256 + t;
    xb[j] = Xfull[s * NN + n] + bias[n];
    X2[0][n] = mml_f(xb[j]);   // X1 = mml(W@0 + xb) = mml(xb)
    X2[1][n] = xb[j];          // accumulation target pre-init
  }
  __syncthreads();

  int c = 0;
  for (int it = 0; it < STEPS - 1; ++it) {   // produces X2..X60
    // scatter: X_next[tgt] += w * X_cur[src]
#pragma unroll
    for (int k = 0; k < EPT; ++k) {
      const int src = (int)(p[k] & 0xffffu);
      const int tgt = (int)(p[k] >> 16);
      atomicAdd(&X2[c ^ 1][tgt], w[k] * X2[c][src]);
    }
    __syncthreads();
    // finalize: apply mml in place; re-init the other buffer for next step
#pragma unroll
    for (int j = 0; j < 8; ++j) {
      const int n = j * 256 + t;
      X2[c ^ 1][n] = mml_f(X2[c ^ 1][n]);
      X2[c][n] = xb[j];
    }
    __syncthreads();
    c ^= 1;
  }

#pragma unroll
  for (int j = 0; j < 8; ++j) {
    const int n = j * 256 + t;
    out[s * NN + n] = X2[c][n];
  }
}

extern "C" void kernel_launch(void* const* d_in, const int* in_sizes, int n_in,
                              void* d_out, int out_size, void* d_ws, size_t ws_size,
                              hipStream_t stream) {
  const float* Xfull = (const float*)d_in[0];   // (B, N) f32
  const float* W     = (const float*)d_in[1];   // (N, N) f32
  const float* bias  = (const float*)d_in[2];   // (N, 1) f32
  float* out = (float*)d_out;

  // ws: ew[EMAX] f32 | epack[EMAX] u32 | cnt[NN] i32 | base[NN] i32
  char* ws = (char*)d_ws;
  float* ew          = (float*)ws;
  unsigned int* epack = (unsigned int*)(ws + (size_t)EMAX * 4);
  int* cnt           = (int*)(ws + (size_t)EMAX * 8);
  int* base          = (int*)(ws + (size_t)EMAX * 8 + (size_t)NN * 4);

  const int B = in_sizes[0] / NN;   // 512

  // zero-pad edge arrays (padding edges: w=0, tgt=src=0 -> harmless +0.0)
  hipMemsetAsync(ew, 0, (size_t)EMAX * 8, stream);  // covers ew + epack
  count_row<<<NN, 64, 0, stream>>>(W, cnt);
  scan2048<<<1, 1024, 0, stream>>>(cnt, base);
  fill_edges<<<NN, 64, 0, stream>>>(W, base, ew, epack);
  sim<<<B, 256, 0, stream>>>(Xfull, bias, ew, epack, out);
}

// Round 5
// 443.026 us; speedup vs baseline: 4.5866x; 4.5866x over previous
//
#include <hip/hip_runtime.h>

// SignalingModel: X_{t+1} = mml(W @ X_t + X_bias), 60 steps, W 0.24% sparse.
// R2: register-resident SORTED edge list, 40 consecutive edges/thread,
// in-register segmented reduction -> LDS atomicAdd only at run boundaries
// (~9/thread instead of 40). float4 finalize/init/output.

#define NN 2048
#define STEPS 60
#define LEAKV 0.01f
#define EMAX 10240          // E; actual nnz <= EMAX (duplicate (tgt,src) collapse)
#define EPT 40              // EMAX / 256 edges per sim thread

__device__ __forceinline__ float mml_f(float x) {
  if (x < 0.0f)      return LEAKV * x;
  else if (x < 0.5f) return x;
  else               return 1.0f - 0.25f / x;
}

// --- build pipeline (unchanged from R1; produces edges sorted by (tgt,src)) ---

__global__ __launch_bounds__(64) void count_row(const float* __restrict__ W,
                                                int* __restrict__ cnt) {
  const int n = blockIdx.x, lane = threadIdx.x;
  int c = 0;
  for (int c0 = 0; c0 < NN; c0 += 64) {
    float w = W[n * NN + c0 + lane];
    c += __popcll(__ballot(w != 0.0f));
  }
  if (lane == 0) cnt[n] = c;
}

__global__ __launch_bounds__(1024) void scan2048(const int* __restrict__ cnt,
                                                 int* __restrict__ base) {
  __shared__ int sb[2][NN];
  const int t = threadIdx.x;
  sb[0][t] = cnt[t];
  sb[0][t + 1024] = cnt[t + 1024];
  __syncthreads();
  int p = 0;
  for (int off = 1; off < NN; off <<= 1) {
    int i0 = t, i1 = t + 1024;
    sb[p ^ 1][i0] = sb[p][i0] + (i0 >= off ? sb[p][i0 - off] : 0);
    sb[p ^ 1][i1] = sb[p][i1] + (i1 >= off ? sb[p][i1 - off] : 0);
    __syncthreads();
    p ^= 1;
  }
  base[t] = sb[p][t] - cnt[t];
  base[t + 1024] = sb[p][t + 1024] - cnt[t + 1024];
}

__global__ __launch_bounds__(64) void fill_edges(const float* __restrict__ W,
                                                 const int* __restrict__ base,
                                                 float* __restrict__ ew,
                                                 unsigned int* __restrict__ epack) {
  const int n = blockIdx.x, lane = threadIdx.x;
  const int b = base[n];
  int off = 0;
  for (int c0 = 0; c0 < NN; c0 += 64) {
    float w = W[n * NN + c0 + lane];
    unsigned long long m = __ballot(w != 0.0f);
    if (w != 0.0f) {
      int e = b + off + __popcll(m & ((1ull << lane) - 1ull));
      ew[e] = w;
      epack[e] = ((unsigned)n << 16) | (unsigned)(c0 + lane);
    }
    off += __popcll(m);
  }
}

// --- simulation -----------------------------------------------------------
// one block per sample; state ping-pong in LDS; 40 consecutive sorted edges
// per thread in registers; segmented-run scatter (atomic only at run ends).
__global__ __launch_bounds__(256) void sim(const float* __restrict__ Xfull,
                                           const float* __restrict__ bias,
                                           const float* __restrict__ ew,
                                           const unsigned int* __restrict__ epack,
                                           float* __restrict__ out) {
  __shared__ float X2[2][NN];
  const int t = (int)threadIdx.x;
  const int s = (int)blockIdx.x;

  // consecutive edges -> per-thread runs of equal target
  float w[EPT];
  unsigned int p[EPT];
#pragma unroll
  for (int k = 0; k < EPT; ++k) {
    w[k] = ew[t * EPT + k];
    p[k] = epack[t * EPT + k];
  }

  // thread owns 8 CONTIGUOUS nodes [8t, 8t+8) -> float4 LDS/global ops
  float4 xbv[2];
  {
    const float4* xf4 = (const float4*)&Xfull[s * NN + t * 8];
    const float4* bi4 = (const float4*)&bias[t * 8];
    float4 a = xf4[0], b4 = xf4[1];
    float4 ba = bi4[0], bb = bi4[1];
    a.x += ba.x; a.y += ba.y; a.z += ba.z; a.w += ba.w;
    b4.x += bb.x; b4.y += bb.y; b4.z += bb.z; b4.w += bb.w;
    xbv[0] = a; xbv[1] = b4;
    float4* c0 = (float4*)&X2[0][t * 8];
    float4* c1 = (float4*)&X2[1][t * 8];
    float4 m0 = make_float4(mml_f(a.x), mml_f(a.y), mml_f(a.z), mml_f(a.w));
    float4 m1 = make_float4(mml_f(b4.x), mml_f(b4.y), mml_f(b4.z), mml_f(b4.w));
    c0[0] = m0; c0[1] = m1;   // X1 = mml(xb)
    c1[0] = a;  c1[1] = b4;   // accumulation target pre-init = xb
  }
  __syncthreads();

  int c = 0;
  for (int it = 0; it < STEPS - 1; ++it) {   // produces X2..X60
    // segmented gather-scatter: run += w*X[src]; on run end, one atomicAdd
    float run = 0.0f;
#pragma unroll
    for (int k = 0; k < EPT; ++k) {
      run += w[k] * X2[c][p[k] & 0xffffu];
      const bool end = (k == EPT - 1) || (((p[k] ^ p[k + 1]) >> 16) != 0u);
      if (end) {
        atomicAdd(&X2[c ^ 1][p[k] >> 16], run);
        run = 0.0f;
      }
    }
    __syncthreads();
    // finalize next state (mml in place) + re-init the just-consumed buffer
    {
      float4* nx = (float4*)&X2[c ^ 1][t * 8];
      float4* cu = (float4*)&X2[c][t * 8];
      float4 a = nx[0], b4 = nx[1];
      a = make_float4(mml_f(a.x), mml_f(a.y), mml_f(a.z), mml_f(a.w));
      b4 = make_float4(mml_f(b4.x), mml_f(b4.y), mml_f(b4.z), mml_f(b4.w));
      nx[0] = a; nx[1] = b4;
      cu[0] = xbv[0]; cu[1] = xbv[1];
    }
    __syncthreads();
    c ^= 1;
  }

  {
    float4* src4 = (float4*)&X2[c][t * 8];
    float4* dst4 = (float4*)&out[s * NN + t * 8];
    dst4[0] = src4[0];
    dst4[1] = src4[1];
  }
}

extern "C" void kernel_launch(void* const* d_in, const int* in_sizes, int n_in,
                              void* d_out, int out_size, void* d_ws, size_t ws_size,
                              hipStream_t stream) {
  const float* Xfull = (const float*)d_in[0];   // (B, N) f32
  const float* W     = (const float*)d_in[1];   // (N, N) f32
  const float* bias  = (const float*)d_in[2];   // (N, 1) f32
  float* out = (float*)d_out;

  // ws: ew[EMAX] f32 | epack[EMAX] u32 | cnt[NN] i32 | base[NN] i32
  char* ws = (char*)d_ws;
  float* ew           = (float*)ws;
  unsigned int* epack = (unsigned int*)(ws + (size_t)EMAX * 4);
  int* cnt            = (int*)(ws + (size_t)EMAX * 8);
  int* base           = (int*)(ws + (size_t)EMAX * 8 + (size_t)NN * 4);

  const int B = in_sizes[0] / NN;   // 512

  // zero-pad edge arrays (padding: w=0, tgt=src=0 -> contributes exact +0.0)
  hipMemsetAsync(ew, 0, (size_t)EMAX * 8, stream);  // covers ew + epack
  count_row<<<NN, 64, 0, stream>>>(W, cnt);
  scan2048<<<1, 1024, 0, stream>>>(cnt, base);
  fill_edges<<<NN, 64, 0, stream>>>(W, base, ew, epack);
  sim<<<B, 256, 0, stream>>>(Xfull, bias, ew, epack, out);
}